// Round 8
// baseline (92395.691 us; speedup 1.0000x reference)
//
#include <hip/hip_runtime.h>
#include <hip/hip_cooperative_groups.h>
#include <math.h>

namespace cg = cooperative_groups;

#define BB   128
#define TT   512
#define INX  3
#define AA   77
#define HH   512
#define KWD  10
#define KMD  20
#define UU   64
#define OUTD 121          // 6*KM+1
#define IN1  80           // INX+AA
#define IN2  592          // INX+AA+HH

// layout: 512 WGs x 256 threads; thread = m(8) x j(16) x kq(2)
#define MT   8            // batch rows per WG
#define NJ   16           // units per WG
#define GRT  (HH/NJ)      // 32 unit tiles
#define MTL  (BB/MT)      // 16 batch tiles
#define NWG  (GRT*MTL)    // 512

// LDS pitches in floats; (pitch % 32) == 20 keeps m-rows on disjoint bank quads
#define PC1  596          // LSTM1 concat row: 148 f4 (+1 f4 pad)
#define PC3  1108         // LSTM2 concat row: 276 f4 (+1 f4 pad)

#define BH   (BB*HH)      // 65536
#define BA   (BB*AA)      // 9856
#define BKW  (BB*KWD)     // 1280

__device__ __forceinline__ float sigf(float x) { return 1.0f / (1.0f + expf(-x)); }

__device__ __forceinline__ float dot4(float4 w, float4 a) {
    return w.x * a.x + w.y * a.y + w.z * a.z + w.w * a.w;
}

// ---------------- fc2 + output transforms (one batch row, one step) ----------------
// Block-uniform entry (contains block barriers); tid<121 active.
__device__ __forceinline__ void fc2_post(const float* __restrict__ h2r,
                                         const float* __restrict__ W_fc2,
                                         const float* __restrict__ b_fc2,
                                         float* __restrict__ out,
                                         int brow, int tprev, int tid,
                                         float* sY, float* sRed)
{
    if (tid < OUTD) {
        const float4* wr = (const float4*)(W_fc2 + (size_t)tid * HH);
        const float4* hv = (const float4*)h2r;
        float acc = b_fc2[tid];
#pragma unroll 4
        for (int k = 0; k < HH / 4; ++k)
            acc += dot4(wr[k], hv[k]);
        sY[tid] = acc;
    }
    __syncthreads();
    if (tid == 0) {
        float mx = sY[0];
        for (int i = 1; i < KMD; ++i) mx = fmaxf(mx, sY[i]);
        float s = 0.f;
        for (int i = 0; i < KMD; ++i) s += expf(sY[i] - mx);
        sRed[0] = mx; sRed[1] = s;
    }
    __syncthreads();
    if (tid < OUTD) {
        const size_t SZ = (size_t)BB * TT * KMD;
        const size_t bt = (size_t)brow * TT + tprev;
        float y = sY[tid];
        if      (tid <     KMD) out[             bt * KMD + tid          ] = expf(y - sRed[0]) / sRed[1];
        else if (tid < 2 * KMD) out[    SZ +     bt * KMD + (tid -   KMD)] = y;
        else if (tid < 3 * KMD) out[2 * SZ +     bt * KMD + (tid - 2*KMD)] = y;
        else if (tid < 4 * KMD) out[3 * SZ +     bt * KMD + (tid - 3*KMD)] = expf(y);
        else if (tid < 5 * KMD) out[4 * SZ +     bt * KMD + (tid - 4*KMD)] = expf(y);
        else if (tid < 6 * KMD) out[5 * SZ +     bt * KMD + (tid - 5*KMD)] = tanhf(y);
        else                    out[6 * SZ + bt] = sigf(y);
    }
}

// ---------------- LSTM1 phase body (256 threads) ----------------
__device__ __forceinline__ void lstm1_body(
    const float* __restrict__ x,
    const float* __restrict__ Wih1, const float* __restrict__ Whh1,
    const float* __restrict__ bih1, const float* __restrict__ bhh1,
    const float* __restrict__ h1_old, float* __restrict__ h1_new,
    float* __restrict__ c1, const float* __restrict__ w_pre,
    int t, int tid, int grt, int mtl, float* sCat, float* sZp)
{
    const int row0 = mtl * MT, unit0 = grt * NJ;
    // stage [x(3)|w_pre(77)|h1(512)] = 148 f4 per row, 8 rows, 32 lanes/row
    {
        const int r = tid >> 5, cc = tid & 31;
        const int b = row0 + r;
        float* rowp = sCat + r * PC1;
        const float4* s1 = (const float4*)(h1_old + (size_t)b * HH);
        float4* d1 = (float4*)(rowp + IN1);
        for (int i = cc; i < HH / 4; i += 32) d1[i] = s1[i];
        for (int i = cc; i < IN1; i += 32)
            rowp[i] = (i < INX) ? x[((size_t)b * TT + t) * INX + i]
                                : w_pre[(size_t)b * AA + (i - INX)];
    }
    __syncthreads();
    // GEMM: thread (m, j, kq) does 4 gates over K-half (74 f4 each)
    {
        const int m = tid & 7, j = (tid >> 3) & 15, kq = tid >> 7;
        const int i0 = kq * 74, i1 = i0 + 74;
        const int u = unit0 + j;
        float a0 = 0.f, a1 = 0.f, a2 = 0.f, a3 = 0.f;
        const float4* sc = (const float4*)(sCat + m * PC1);

        const float4* w0a = (const float4*)Wih1 + (size_t)u * 20;
        const float4* w1a = (const float4*)Wih1 + (size_t)(HH + u) * 20;
        const float4* w2a = (const float4*)Wih1 + (size_t)(2 * HH + u) * 20;
        const float4* w3a = (const float4*)Wih1 + (size_t)(3 * HH + u) * 20;
        const int aEnd = (i1 < 20) ? i1 : 20;
        for (int i = i0; i < aEnd; ++i) {            // only kq==0 enters
            float4 a = sc[i];
            a0 += dot4(w0a[i], a); a1 += dot4(w1a[i], a);
            a2 += dot4(w2a[i], a); a3 += dot4(w3a[i], a);
        }
        const float4* w0b = (const float4*)Whh1 + (size_t)u * 128;
        const float4* w1b = (const float4*)Whh1 + (size_t)(HH + u) * 128;
        const float4* w2b = (const float4*)Whh1 + (size_t)(2 * HH + u) * 128;
        const float4* w3b = (const float4*)Whh1 + (size_t)(3 * HH + u) * 128;
        const int bSt = (i0 > 20) ? i0 : 20;
#pragma unroll 4
        for (int i = bSt; i < i1; ++i) {
            float4 a = sc[i];
            const int k = i - 20;
            a0 += dot4(w0b[k], a); a1 += dot4(w1b[k], a);
            a2 += dot4(w2b[k], a); a3 += dot4(w3b[k], a);
        }
        float* zr = sZp + ((kq << 3) | m) * 68;
        zr[j]      = a0;
        zr[16 + j] = a1;
        zr[32 + j] = a2;
        zr[48 + j] = a3;
    }
    __syncthreads();
    // cell: 128 threads, thread = (m = tid>>4, j = tid&15)
    if (tid < MT * NJ) {
        const int m = tid >> 4, j = tid & 15;
        const int u = unit0 + j;
        const float* z0 = sZp + m * 68;
        const float* z1 = sZp + (8 + m) * 68;
        float z[4];
#pragma unroll
        for (int g = 0; g < 4; ++g) {
            const int wr = g * HH + u;
            z[g] = bih1[wr] + bhh1[wr] + z0[g * 16 + j] + z1[g * 16 + j];
        }
        const size_t gi = (size_t)(row0 + m) * HH + u;
        const float cold = c1[gi];
        const float cn = sigf(z[1]) * cold + sigf(z[0]) * tanhf(z[2]);
        c1[gi] = cn;
        h1_new[gi] = sigf(z[3]) * tanhf(cn);
    }
}

// ---------------- LSTM2 phase body (256 threads) ----------------
__device__ __forceinline__ void lstm2_body(
    const float* __restrict__ x,
    const float* __restrict__ Wih2, const float* __restrict__ Whh2,
    const float* __restrict__ bih2, const float* __restrict__ bhh2,
    const float* __restrict__ h1_cur, const float* __restrict__ w_cur,
    const float* __restrict__ h2_old, float* __restrict__ h2_new,
    float* __restrict__ c2,
    int t, int tid, int grt, int mtl, float* sCat, float* sZp)
{
    const int row0 = mtl * MT, unit0 = grt * NJ;
    // stage [x(3)|w(77)|h1(512)|h2(512)] = 276 f4 per row
    {
        const int r = tid >> 5, cc = tid & 31;
        const int b = row0 + r;
        float* rowp = sCat + r * PC3;
        const float4* s1 = (const float4*)(h1_cur + (size_t)b * HH);
        const float4* s2 = (const float4*)(h2_old + (size_t)b * HH);
        float4* d1 = (float4*)(rowp + IN1);      // cols 80..591
        float4* d2 = (float4*)(rowp + IN2);      // cols 592..1103
        for (int i = cc; i < HH / 4; i += 32) { d1[i] = s1[i]; d2[i] = s2[i]; }
        for (int i = cc; i < IN1; i += 32)
            rowp[i] = (i < INX) ? x[((size_t)b * TT + t) * INX + i]
                                : w_cur[(size_t)b * AA + (i - INX)];
    }
    __syncthreads();
    // GEMM: thread (m, j, kq) over K-half (138 f4 each)
    {
        const int m = tid & 7, j = (tid >> 3) & 15, kq = tid >> 7;
        const int i0 = kq * 138, i1 = i0 + 138;
        const int u = unit0 + j;
        float a0 = 0.f, a1 = 0.f, a2 = 0.f, a3 = 0.f;
        const float4* sc = (const float4*)(sCat + m * PC3);

        const float4* w0a = (const float4*)Wih2 + (size_t)u * 148;
        const float4* w1a = (const float4*)Wih2 + (size_t)(HH + u) * 148;
        const float4* w2a = (const float4*)Wih2 + (size_t)(2 * HH + u) * 148;
        const float4* w3a = (const float4*)Wih2 + (size_t)(3 * HH + u) * 148;
        const int aEnd = (i1 < 148) ? i1 : 148;
#pragma unroll 4
        for (int i = i0; i < aEnd; ++i) {
            float4 a = sc[i];
            a0 += dot4(w0a[i], a); a1 += dot4(w1a[i], a);
            a2 += dot4(w2a[i], a); a3 += dot4(w3a[i], a);
        }
        const float4* w0b = (const float4*)Whh2 + (size_t)u * 128;
        const float4* w1b = (const float4*)Whh2 + (size_t)(HH + u) * 128;
        const float4* w2b = (const float4*)Whh2 + (size_t)(2 * HH + u) * 128;
        const float4* w3b = (const float4*)Whh2 + (size_t)(3 * HH + u) * 128;
        const int bSt = (i0 > 148) ? i0 : 148;
#pragma unroll 4
        for (int i = bSt; i < i1; ++i) {
            float4 a = sc[i];
            const int k = i - 148;
            a0 += dot4(w0b[k], a); a1 += dot4(w1b[k], a);
            a2 += dot4(w2b[k], a); a3 += dot4(w3b[k], a);
        }
        float* zr = sZp + ((kq << 3) | m) * 68;
        zr[j]      = a0;
        zr[16 + j] = a1;
        zr[32 + j] = a2;
        zr[48 + j] = a3;
    }
    __syncthreads();
    if (tid < MT * NJ) {
        const int m = tid >> 4, j = tid & 15;
        const int u = unit0 + j;
        const float* z0 = sZp + m * 68;
        const float* z1 = sZp + (8 + m) * 68;
        float z[4];
#pragma unroll
        for (int g = 0; g < 4; ++g) {
            const int wr = g * HH + u;
            z[g] = bih2[wr] + bhh2[wr] + z0[g * 16 + j] + z1[g * 16 + j];
        }
        const size_t gi = (size_t)(row0 + m) * HH + u;
        const float cold = c2[gi];
        const float cn = sigf(z[1]) * cold + sigf(z[0]) * tanhf(z[2]);
        c2[gi] = cn;
        h2_new[gi] = sigf(z[3]) * tanhf(cn);
    }
}

// ---------------- attention phase body (256 threads, one batch row) ----------------
__device__ __forceinline__ void attn_body(
    const float* __restrict__ c_seq,
    const float* __restrict__ W_abk, const float* __restrict__ b_abk,
    const float* __restrict__ h1_cur,
    const float* __restrict__ kap_old, float* __restrict__ kap_new,
    float* __restrict__ w_new, int b, int tid, float* sH1, float* zf)
{
    float* sAbk = zf;            // 32
    float* sAl  = zf + 32;       // 10
    float* sBe  = zf + 48;       // 10
    float* sKa  = zf + 64;       // 10
    float* sPhi = zf + 80;       // 64

    if (tid < HH / 4)
        ((float4*)sH1)[tid] = ((const float4*)(h1_cur + (size_t)b * HH))[tid];
    __syncthreads();

    {   // abk: 30 rows x K=512, 8-way K-split per row
        const int o = tid >> 3, kk = tid & 7;
        float acc = 0.f;
        if (o < 3 * KWD) {
            const float4* wp = (const float4*)(W_abk + (size_t)o * HH) + kk * 16;
            const float4* hp = (const float4*)sH1 + kk * 16;
#pragma unroll
            for (int k = 0; k < 16; ++k)
                acc += dot4(wp[k], hp[k]);
        }
        acc += __shfl_xor(acc, 1);
        acc += __shfl_xor(acc, 2);
        acc += __shfl_xor(acc, 4);
        if (o < 3 * KWD && kk == 0) sAbk[o] = acc + b_abk[o];
    }
    __syncthreads();

    if (tid < KWD) {
        const float al = expf(sAbk[tid]);
        const float be = expf(sAbk[KWD + tid]);
        const float ka = kap_old[(size_t)b * KWD + tid] + expf(sAbk[2 * KWD + tid]);
        sAl[tid] = al; sBe[tid] = be; sKa[tid] = ka;
        kap_new[(size_t)b * KWD + tid] = ka;
    }
    __syncthreads();

    if (tid < UU) {
        const float u = (float)tid;
        float s = 0.f;
#pragma unroll
        for (int k = 0; k < KWD; ++k) {
            const float d = sKa[k] - u;
            s += sAl[k] * expf(-sBe[k] * d * d);
        }
        sPhi[tid] = s;
    }
    __syncthreads();

    if (tid < AA) {
        float s = 0.f;
        const float* cp = c_seq + (size_t)b * UU * AA + tid;
#pragma unroll 4
        for (int u = 0; u < UU; ++u) s += sPhi[u] * cp[(size_t)u * AA];
        w_new[(size_t)b * AA + tid] = s;
    }
}

// ================= persistent cooperative kernel =================
// Per step: A (LSTM1) | gsync | B (attn WG<128; fc2(t-1) WG 128..255) | gsync |
// C (LSTM2). No sync after C: C(t)/A(t+1) touch disjoint buffers
// (A(t+1) writes h1b[p],c1; C(t) writes h2b[1-p],c2; reads don't intersect writes).
__global__ __launch_bounds__(256, 2) void fused(
    const float* __restrict__ x, const float* __restrict__ c_seq,
    const float* __restrict__ Wih1, const float* __restrict__ Whh1,
    const float* __restrict__ bih1, const float* __restrict__ bhh1,
    const float* __restrict__ Wih2, const float* __restrict__ Whh2,
    const float* __restrict__ bih2, const float* __restrict__ bhh2,
    const float* __restrict__ W_abk, const float* __restrict__ b_abk,
    const float* __restrict__ W_fc2, const float* __restrict__ b_fc2,
    float* __restrict__ h1b, float* __restrict__ h2b,
    float* __restrict__ c1, float* __restrict__ c2,
    float* __restrict__ kapb, float* __restrict__ wbuf,
    float* __restrict__ out)
{
    __shared__ float sCat[MT * PC3];     // 35.4 KB (A uses stride PC1, B uses as sH1)
    __shared__ float sZp[2 * MT * 68];   // 4.4 KB
    __shared__ float sAux[OUTD + 8];

    const int tid = threadIdx.x;
    const int wg  = blockIdx.x;
    const int grt = wg & 31, mtl = wg >> 5;
    cg::grid_group gg = cg::this_grid();

    for (int t = 0; t < TT; ++t) {
        const int p = t & 1;
        const float* h1_old  = h1b  + (size_t)p * BH;
        float*       h1_new  = h1b  + (size_t)(1 - p) * BH;
        const float* h2_old  = h2b  + (size_t)p * BH;
        float*       h2_new  = h2b  + (size_t)(1 - p) * BH;
        const float* w_pre   = wbuf + (size_t)p * BA;
        float*       w_new   = wbuf + (size_t)(1 - p) * BA;
        const float* kap_old = kapb + (size_t)p * BKW;
        float*       kap_new = kapb + (size_t)(1 - p) * BKW;

        lstm1_body(x, Wih1, Whh1, bih1, bhh1, h1_old, h1_new, c1, w_pre,
                   t, tid, grt, mtl, sCat, sZp);
        gg.sync();

        if (wg < BB) {
            attn_body(c_seq, W_abk, b_abk, h1_new, kap_old, kap_new, w_new,
                      wg, tid, sCat, sZp);
        } else if (wg < 2 * BB) {
            if (t > 0)
                fc2_post(h2_old + (size_t)(wg - BB) * HH, W_fc2, b_fc2, out,
                         wg - BB, t - 1, tid, sAux, sAux + OUTD);
        }
        gg.sync();

        lstm2_body(x, Wih2, Whh2, bih2, bhh2, h1_new, w_new, h2_old, h2_new, c2,
                   t, tid, grt, mtl, sCat, sZp);
        // no grid sync: C(t) ∥ A(t+1) is race-free (see header comment)
    }

    gg.sync();
    if (wg < BB)   // final fc2: TT even -> last h2 is h2b[0]
        fc2_post(h2b + (size_t)wg * HH, W_fc2, b_fc2, out, wg, TT - 1, tid,
                 sAux, sAux + OUTD);
}

// ================= fallback kernels (round-5 structure, 256 threads) =================
__global__ __launch_bounds__(256) void k1(
    const float* __restrict__ x,
    const float* __restrict__ Wih1, const float* __restrict__ Whh1,
    const float* __restrict__ bih1, const float* __restrict__ bhh1,
    const float* __restrict__ W_fc2, const float* __restrict__ b_fc2,
    const float* __restrict__ h1_old, float* __restrict__ h1_new,
    float* __restrict__ c1,
    const float* __restrict__ w_pre, const float* __restrict__ h2_prev,
    float* __restrict__ out, int t)
{
    __shared__ float sCat[MT * PC1];
    __shared__ float sZp[2 * MT * 68];
    __shared__ float sAux[OUTD + 8];
    const int tid = threadIdx.x, grt = blockIdx.x, mtl = blockIdx.y;
    lstm1_body(x, Wih1, Whh1, bih1, bhh1, h1_old, h1_new, c1, w_pre,
               t, tid, grt, mtl, sCat, sZp);
    if (t > 0 && grt < MT)
        fc2_post(h2_prev + (size_t)(mtl * MT + grt) * HH, W_fc2, b_fc2, out,
                 mtl * MT + grt, t - 1, tid, sAux, sAux + OUTD);
}

__global__ __launch_bounds__(256) void k2(
    const float* __restrict__ c_seq,
    const float* __restrict__ W_abk, const float* __restrict__ b_abk,
    const float* __restrict__ h1_cur,
    const float* __restrict__ kap_old, float* __restrict__ kap_new,
    float* __restrict__ w_new)
{
    __shared__ float sH1[HH];
    __shared__ float zf[160];
    attn_body(c_seq, W_abk, b_abk, h1_cur, kap_old, kap_new, w_new,
              blockIdx.x, threadIdx.x, sH1, zf);
}

__global__ __launch_bounds__(256) void k3(
    const float* __restrict__ x,
    const float* __restrict__ Wih2, const float* __restrict__ Whh2,
    const float* __restrict__ bih2, const float* __restrict__ bhh2,
    const float* __restrict__ h1_cur, const float* __restrict__ w_cur,
    const float* __restrict__ h2_old, float* __restrict__ h2_new,
    float* __restrict__ c2, int t)
{
    __shared__ float sCat[MT * PC3];
    __shared__ float sZp[2 * MT * 68];
    lstm2_body(x, Wih2, Whh2, bih2, bhh2, h1_cur, w_cur, h2_old, h2_new, c2,
               t, threadIdx.x, blockIdx.x, blockIdx.y, sCat, sZp);
}

__global__ __launch_bounds__(128) void fc2_final(
    const float* __restrict__ h2_last,
    const float* __restrict__ W_fc2, const float* __restrict__ b_fc2,
    float* __restrict__ out)
{
    __shared__ float sAux[OUTD + 8];
    fc2_post(h2_last + (size_t)blockIdx.x * HH, W_fc2, b_fc2, out,
             blockIdx.x, TT - 1, threadIdx.x, sAux, sAux + OUTD);
}

extern "C" void kernel_launch(void* const* d_in, const int* in_sizes, int n_in,
                              void* d_out, int out_size, void* d_ws, size_t ws_size,
                              hipStream_t stream) {
    const float* x     = (const float*)d_in[0];
    const float* c_seq = (const float*)d_in[1];
    const float* Wih1  = (const float*)d_in[2];
    const float* Whh1  = (const float*)d_in[3];
    const float* bih1  = (const float*)d_in[4];
    const float* bhh1  = (const float*)d_in[5];
    const float* Wih2  = (const float*)d_in[6];
    const float* Whh2  = (const float*)d_in[7];
    const float* bih2  = (const float*)d_in[8];
    const float* bhh2  = (const float*)d_in[9];
    const float* W_abk = (const float*)d_in[10];
    const float* b_abk = (const float*)d_in[11];
    const float* W_fc2 = (const float*)d_in[12];
    const float* b_fc2 = (const float*)d_in[13];
    float* out = (float*)d_out;

    float* ws  = (float*)d_ws;
    float* h1b = ws;                     // 2*BH (double buffer)
    float* h2b = ws + 2 * BH;            // 2*BH
    float* c1  = ws + 4 * BH;            // BH
    float* c2  = ws + 5 * BH;            // BH
    float* kap = ws + 6 * BH;            // 2*BKW
    float* wb  = ws + 6 * BH + 2 * BKW;  // 2*BA
    const size_t used = (size_t)6 * BH + 2 * BKW + 2 * BA;

    hipMemsetAsync(d_ws, 0, used * sizeof(float), stream);

    void* args[] = {
        (void*)&x, (void*)&c_seq,
        (void*)&Wih1, (void*)&Whh1, (void*)&bih1, (void*)&bhh1,
        (void*)&Wih2, (void*)&Whh2, (void*)&bih2, (void*)&bhh2,
        (void*)&W_abk, (void*)&b_abk, (void*)&W_fc2, (void*)&b_fc2,
        (void*)&h1b, (void*)&h2b, (void*)&c1, (void*)&c2,
        (void*)&kap, (void*)&wb, (void*)&out
    };
    hipError_t err = hipLaunchCooperativeKernel((const void*)fused, dim3(NWG),
                                                dim3(256), args, 0, stream);
    if (err != hipSuccess) {
        (void)hipGetLastError();   // clear sticky error; run fallback path
        const dim3 grid(GRT, MTL), blk(256);
        for (int t = 0; t < TT; ++t) {
            const int p = t & 1;
            k1<<<grid, blk, 0, stream>>>(x, Wih1, Whh1, bih1, bhh1, W_fc2, b_fc2,
                                         h1b + (size_t)p * BH, h1b + (size_t)(1 - p) * BH, c1,
                                         wb + (size_t)p * BA, h2b + (size_t)p * BH, out, t);
            k2<<<dim3(BB), blk, 0, stream>>>(c_seq, W_abk, b_abk,
                                             h1b + (size_t)(1 - p) * BH,
                                             kap + (size_t)p * BKW, kap + (size_t)(1 - p) * BKW,
                                             wb + (size_t)(1 - p) * BA);
            k3<<<grid, blk, 0, stream>>>(x, Wih2, Whh2, bih2, bhh2,
                                         h1b + (size_t)(1 - p) * BH, wb + (size_t)(1 - p) * BA,
                                         h2b + (size_t)p * BH, h2b + (size_t)(1 - p) * BH, c2, t);
        }
        fc2_final<<<dim3(BB), dim3(128), 0, stream>>>(h2b, W_fc2, b_fc2, out);
    }
}